// Round 8
// baseline (19303.210 us; speedup 1.0000x reference)
//
#include <hip/hip_runtime.h>
#include <math.h>

#define BB 256
#define TT 256
#define HH 512
#define G4 2048
#define IN0_ 519

typedef __bf16 bf16x8 __attribute__((ext_vector_type(8)));
typedef float  f32x4  __attribute__((ext_vector_type(4)));
typedef unsigned short ushort;

__device__ __forceinline__ float sigf(float x) { return 1.0f / (1.0f + expf(-x)); }
__device__ __forceinline__ float leaky(float x) { return x > 0.f ? x : 0.2f * x; }

__device__ __forceinline__ ushort f2b(float x) {
    union { float f; unsigned int u; } v; v.f = x;
    unsigned int r = v.u + 0x7fffu + ((v.u >> 16) & 1u);   // RNE
    return (ushort)(r >> 16);
}

__device__ __forceinline__ float block_sum(float v, float* red, int tid) {
    red[tid] = v; __syncthreads();
    for (int s = 128; s > 0; s >>= 1) {
        if (tid < s) red[tid] += red[tid + s];
        __syncthreads();
    }
    float r = red[0];
    __syncthreads();
    return r;
}

// swizzled LDS A-tile helpers: 16 rows x 512 bf16 (1KB/row), 16B granules
// byte offset within row bo, swizzle: bo ^ (((row ^ (bo>>6)) & 7) << 4)
#define SWZB(row, bo) ((bo) ^ (((((row) ^ ((bo) >> 6)) & 7)) << 4))
#define LDA(Abuf, lr_, lk_, kt_) \
    (*(const bf16x8*)&Abuf[((lr_) * 1024 + SWZB((lr_), (kt_)*64 + (lk_)*16)) >> 1])

__device__ __forceinline__ void stageA(ushort* dst, const ushort* src, int m0, int tid) {
    int row = tid >> 4;
    int lanebo = (tid & 15) * 64;
    const ushort* sp = src + (size_t)(m0 + row) * HH;
    #pragma unroll
    for (int j = 0; j < 4; j++) {
        int b2 = lanebo + j * 16;
        uint4 v = *(const uint4*)(sp + (b2 >> 1));
        *(uint4*)&dst[((row * 1024) + SWZB(row, b2)) >> 1] = v;
    }
}

// team barrier: only the 16 blocks of one team participate (independent teams,
// no grid-wide sync anywhere -> plain launch is sufficient, no cooperative needed)
__device__ __forceinline__ void team_barrier(unsigned* cnt, unsigned target) {
    __syncthreads();
    if (threadIdx.x == 0) {
        __threadfence();
        __hip_atomic_fetch_add(cnt, 1u, __ATOMIC_RELEASE, __HIP_MEMORY_SCOPE_AGENT);
        while (__hip_atomic_load(cnt, __ATOMIC_ACQUIRE, __HIP_MEMORY_SCOPE_AGENT) < target)
            __builtin_amdgcn_s_sleep(2);
        __threadfence();
    }
    __syncthreads();
}

// shuffled weight layout: idx = ((jgt*16 + kt)*64 + lane)*8 + e
// holds W[jgt*16 + (lane&15)][kt*32 + (lane>>4)*8 + e]
#define SHIDX(jgt, kt, l_) ((((size_t)(jgt) * 16 + (kt)) * 64 + (l_)) * 8)

// ---------------- prep: convert + shuffle all weights ----------------
__global__ __launch_bounds__(256) void prep_all(
    const float* __restrict__ Whh0, const float* __restrict__ Wih1,
    const float* __restrict__ Whh1, const float* __restrict__ Wih0,
    const float* __restrict__ ow1,
    ushort* __restrict__ w0s, ushort* __restrict__ w1s,
    ushort* __restrict__ w2s, ushort* __restrict__ wi0s,
    ushort* __restrict__ ow1s, float* __restrict__ Wf)
{
    size_t idx = (size_t)blockIdx.x * 256 + threadIdx.x;
    const size_t M = 1u << 20;
    if (idx < 4 * M) {
        int m = (int)(idx >> 20);
        unsigned i = (unsigned)(idx & (M - 1));
        int e = i & 7, ll = (i >> 3) & 63, kt = (i >> 9) & 15, jgt = i >> 13;
        int jg = jgt * 16 + (ll & 15);
        int k  = kt * 32 + ((ll >> 4) << 3) + e;
        float v;
        if (m == 0)      v = Whh0[(size_t)jg * 512 + k];
        else if (m == 1) v = Wih1[(size_t)jg * 512 + k];
        else if (m == 2) v = Whh1[(size_t)jg * 512 + k];
        else             v = Wih0[(size_t)jg * IN0_ + 3 + k];
        ushort* dst = (m == 0) ? w0s : (m == 1) ? w1s : (m == 2) ? w2s : wi0s;
        dst[i] = f2b(v);
    } else if (idx < 4 * M + 131072) {
        unsigned i = (unsigned)(idx - 4 * M);
        int e = i & 7, ll = (i >> 3) & 63, kt = (i >> 9) & 15, jgt = i >> 13; // jgt<16
        int jg = jgt * 16 + (ll & 15);
        int k  = kt * 32 + ((ll >> 4) << 3) + e;
        ow1s[i] = f2b(ow1[(size_t)jg * 512 + k]);
    } else if (idx < 4 * M + 131072 + 2048) {
        int jrow = (int)(idx - (4 * M + 131072));
        const int fc[7] = {0, 1, 2, 515, 516, 517, 518};
        #pragma unroll
        for (int f = 0; f < 7; f++) Wf[jrow * 8 + f] = Wih0[(size_t)jrow * IN0_ + fc[f]];
        Wf[jrow * 8 + 7] = 0.f;
    }
}

// ---------------- condition encoder (writes bf16 cond) ----------------
__global__ __launch_bounds__(256) void cond_encoder(
    const float* __restrict__ start, const float* __restrict__ end,
    const float* __restrict__ z,
    const float* __restrict__ w1, const float* __restrict__ b1,
    const float* __restrict__ g1, const float* __restrict__ be1,
    const float* __restrict__ w2, const float* __restrict__ b2,
    const float* __restrict__ g2, const float* __restrict__ be2,
    ushort* __restrict__ condb)
{
    __shared__ float ci[70];
    __shared__ float xr[512];
    __shared__ float red[256];
    int b = blockIdx.x, tid = threadIdx.x;
    if (tid == 0) {
        float sx = start[2*b], sy = start[2*b+1];
        float ex = end[2*b],   ey = end[2*b+1];
        float dx = ex - sx, dy = ey - sy;
        ci[0]=sx; ci[1]=sy; ci[2]=ex; ci[3]=ey;
        ci[4]=sqrtf(dx*dx + dy*dy + 1e-8f);
        ci[5]=atan2f(dy, dx);
    }
    if (tid < 64) ci[6+tid] = z[b*64 + tid];
    __syncthreads();

    float pre0 = b1[tid], pre1 = b1[tid+256];
    {
        const float* r0 = w1 + (size_t)tid*70;
        const float* r1 = w1 + (size_t)(tid+256)*70;
        for (int k = 0; k < 70; k++) { float c = ci[k]; pre0 += c*r0[k]; pre1 += c*r1[k]; }
    }
    float m = block_sum(pre0+pre1, red, tid) * (1.f/512.f);
    float d0 = pre0-m, d1 = pre1-m;
    float v = block_sum(d0*d0 + d1*d1, red, tid) * (1.f/512.f);
    float rstd = rsqrtf(v + 1e-5f);
    xr[tid]     = leaky(d0*rstd*g1[tid]     + be1[tid]);
    xr[tid+256] = leaky(d1*rstd*g1[tid+256] + be1[tid+256]);
    __syncthreads();

    float q0 = b2[tid], q1 = b2[tid+256];
    {
        const float4* r0 = (const float4*)(w2 + (size_t)tid*512);
        const float4* r1 = (const float4*)(w2 + (size_t)(tid+256)*512);
        const float4* xv4 = (const float4*)xr;
        for (int q = 0; q < 128; q++) {
            float4 xv = xv4[q];
            float4 wa = r0[q], wb = r1[q];
            q0 += xv.x*wa.x + xv.y*wa.y + xv.z*wa.z + xv.w*wa.w;
            q1 += xv.x*wb.x + xv.y*wb.y + xv.z*wb.z + xv.w*wb.w;
        }
    }
    m = block_sum(q0+q1, red, tid) * (1.f/512.f);
    d0 = q0-m; d1 = q1-m;
    v = block_sum(d0*d0 + d1*d1, red, tid) * (1.f/512.f);
    rstd = rsqrtf(v + 1e-5f);
    condb[(size_t)b*512 + tid]     = f2b(leaky(d0*rstd*g2[tid]     + be2[tid]));
    condb[(size_t)b*512 + tid+256] = f2b(leaky(d1*rstd*g2[tid+256] + be2[tid+256]));
}

// ---------------- gs0 = cond @ Wih0[:,3:515]^T + bih0 + bhh0 (MFMA) ----------------
__global__ __launch_bounds__(256) void gs0_mfma(
    const ushort* __restrict__ condb, const ushort* __restrict__ wi0s,
    const float* __restrict__ bih0, const float* __restrict__ bhh0,
    float* __restrict__ gs0)
{
    __shared__ ushort A1[16*512];
    int tid = threadIdx.x;
    int bt = blockIdx.x >> 4, ct2 = blockIdx.x & 15;
    int m0 = bt*16, hc0 = ct2*32;
    int wid = tid >> 6, l = tid & 63, lr = l & 15, lk = l >> 4;
    stageA(A1, condb, m0, tid);
    __syncthreads();
    int jgb = wid*512 + hc0;
    float bv0 = bih0[jgb+lr]    + bhh0[jgb+lr];
    float bv1 = bih0[jgb+16+lr] + bhh0[jgb+16+lr];
    f32x4 a0, a1;
    #pragma unroll
    for (int r = 0; r < 4; r++) { a0[r] = bv0; a1[r] = bv1; }
    int jgt = jgb >> 4;
    #pragma unroll
    for (int kt = 0; kt < 16; kt++) {
        bf16x8 av = LDA(A1, lr, lk, kt);
        bf16x8 b0 = *(const bf16x8*)&wi0s[SHIDX(jgt,   kt, l)];
        bf16x8 b1 = *(const bf16x8*)&wi0s[SHIDX(jgt+1, kt, l)];
        a0 = __builtin_amdgcn_mfma_f32_16x16x32_bf16(av, b0, a0, 0, 0, 0);
        a1 = __builtin_amdgcn_mfma_f32_16x16x32_bf16(av, b1, a1, 0, 0, 0);
    }
    #pragma unroll
    for (int r = 0; r < 4; r++) {
        gs0[(size_t)(m0 + lk*4 + r)*G4 + jgb + lr]      = a0[r];
        gs0[(size_t)(m0 + lk*4 + r)*G4 + jgb + 16 + lr] = a1[r];
    }
}

// ---------------- persistent rollout: 256 blocks, independent teams of 16 ----------------
__global__ __launch_bounds__(256, 1) void rollout(
    const ushort* __restrict__ w0s, const ushort* __restrict__ w1s,
    const ushort* __restrict__ w2s, const ushort* __restrict__ ow1s,
    const float* __restrict__ gs0, const float* __restrict__ WfG,
    const float* __restrict__ bih1, const float* __restrict__ bhh1,
    const float* __restrict__ ob1, const float* __restrict__ ow2,
    const float* __restrict__ ob2,
    const float* __restrict__ start, const float* __restrict__ endp,
    const float* __restrict__ init_in, const int* __restrict__ max_len,
    ushort* __restrict__ h0A, ushort* __restrict__ h0B,
    ushort* __restrict__ h1A, ushort* __restrict__ h1B,
    float* __restrict__ outp, unsigned* __restrict__ bar)
{
    __shared__ ushort A1[16*512];
    __shared__ ushort A2[16*512];
    __shared__ float scratch[16*257];       // gates [4][16][33] (phases 1/2) | hid [16][257] (phase 3)
    __shared__ float WfS[4*32*9];
    __shared__ ushort hstage[512];
    __shared__ float feats[16][8];
    __shared__ float posS[16][2], endS[16][2], osumS[16][3];

    int tid = threadIdx.x;
    int blk = blockIdx.x;
    int xcd = blk & 7, wi = blk >> 3;
    int ct = xcd*2 + (wi & 1);   // column-slice id: same-ct blocks share weights & an XCD
    int bt = wi >> 1;            // batch-tile id: team = all 16 ct's of this bt
    int m0 = bt*16, hc0 = ct*32;
    int wid = tid >> 6, l = tid & 63, lr = l & 15, lk = l >> 4;
    unsigned* cnt = bar + bt*16;

    for (int i = tid; i < 4*32*8; i += 256) {
        int g = i >> 8, rem = i & 255, col = rem >> 3, f = rem & 7;
        WfS[(g*32+col)*9 + f] = WfG[(size_t)(g*512 + hc0 + col)*8 + f];
    }
    if (tid < 16) {
        int b = m0 + tid;
        posS[tid][0] = start[2*b]; posS[tid][1] = start[2*b+1];
        endS[tid][0] = endp[2*b];  endS[tid][1] = endp[2*b+1];
        if (ct == 0) outp[(size_t)BB*TT*3 + b] = (float)max_len[0];
    }
    __syncthreads();
    if (tid < 16) {
        float rx = endS[tid][0]-posS[tid][0], ry = endS[tid][1]-posS[tid][1];
        feats[tid][0]=init_in[0]; feats[tid][1]=init_in[1]; feats[tid][2]=init_in[2];
        feats[tid][3]=rx; feats[tid][4]=ry;
        feats[tid][5]=sqrtf(rx*rx+ry*ry+1e-8f);
        feats[tid][6]=atan2f(ry,rx);
    }

    // one-time register state
    f32x4 gsr[2]; float b1r[2]; float ob1r[4];
    #pragma unroll
    for (int nt = 0; nt < 2; nt++) {
        int jg = wid*512 + hc0 + nt*16 + lr;
        #pragma unroll
        for (int r = 0; r < 4; r++) gsr[nt][r] = gs0[(size_t)(m0 + lk*4 + r)*G4 + jg];
        b1r[nt] = bih1[jg] + bhh1[jg];
    }
    #pragma unroll
    for (int q = 0; q < 4; q++) ob1r[q] = ob1[wid*64 + q*16 + lr];

    // zero own h slices (ping buffers)
    for (int i = tid; i < 512; i += 256) {
        int row = i >> 5, col = i & 31;
        h0A[(size_t)(m0+row)*HH + hc0 + col] = 0;
        h1A[(size_t)(m0+row)*HH + hc0 + col] = 0;
    }
    float c00 = 0.f, c01 = 0.f, c10 = 0.f, c11 = 0.f;

    unsigned bseq = 1;
    team_barrier(cnt, bseq*16u);

    int jgt0 = wid*32 + ct*2;   // lstm weight-tile base
    #pragma unroll 1
    for (int t = 0; t < TT; t++) {
        const ushort* h0in  = (t & 1) ? h0B : h0A;
        ushort*       h0out = (t & 1) ? h0A : h0B;
        const ushort* h1in  = (t & 1) ? h1B : h1A;
        ushort*       h1out = (t & 1) ? h1A : h1B;

        // ======== phase 1: lstm0 ========
        stageA(A1, h0in, m0, tid);
        __syncthreads();
        {
            f32x4 a0 = gsr[0], a1 = gsr[1];
            #pragma unroll
            for (int kt = 0; kt < 16; kt++) {
                bf16x8 av  = LDA(A1, lr, lk, kt);
                bf16x8 b0  = *(const bf16x8*)&w0s[SHIDX(jgt0,   kt, l)];
                bf16x8 b1v = *(const bf16x8*)&w0s[SHIDX(jgt0+1, kt, l)];
                a0 = __builtin_amdgcn_mfma_f32_16x16x32_bf16(av, b0,  a0, 0, 0, 0);
                a1 = __builtin_amdgcn_mfma_f32_16x16x32_bf16(av, b1v, a1, 0, 0, 0);
            }
            #pragma unroll
            for (int r = 0; r < 4; r++) {
                scratch[(wid*16 + lk*4 + r)*33 + lr]      = a0[r];
                scratch[(wid*16 + lk*4 + r)*33 + 16 + lr] = a1[r];
            }
        }
        __syncthreads();
        #pragma unroll
        for (int s = 0; s < 2; s++) {
            int cell = tid + s*256;
            int row = cell >> 5, col = cell & 31;
            float gv[4];
            #pragma unroll
            for (int g = 0; g < 4; g++) {
                float v = scratch[(g*16 + row)*33 + col];
                const float* wf = &WfS[(g*32 + col)*9];
                #pragma unroll
                for (int f = 0; f < 7; f++) v += feats[row][f] * wf[f];
                gv[g] = v;
            }
            float cold = s ? c01 : c00;
            float cn = sigf(gv[1])*cold + sigf(gv[0])*tanhf(gv[2]);
            if (s) c01 = cn; else c00 = cn;
            hstage[cell] = f2b(sigf(gv[3])*tanhf(cn));
        }
        __syncthreads();
        if (tid < 64) {
            int row = tid >> 2, cc = (tid & 3)*8;
            *(uint4*)&h0out[(size_t)(m0+row)*HH + hc0 + cc] = *(const uint4*)&hstage[row*32 + cc];
        }
        bseq++; team_barrier(cnt, bseq*16u);

        // ======== phase 2: lstm1 ========
        stageA(A1, h0out, m0, tid);
        stageA(A2, h1in,  m0, tid);
        __syncthreads();
        {
            f32x4 a0, a1;
            #pragma unroll
            for (int r = 0; r < 4; r++) { a0[r] = b1r[0]; a1[r] = b1r[1]; }
            #pragma unroll
            for (int kt = 0; kt < 16; kt++) {
                bf16x8 av  = LDA(A1, lr, lk, kt);
                bf16x8 b0  = *(const bf16x8*)&w1s[SHIDX(jgt0,   kt, l)];
                bf16x8 b1v = *(const bf16x8*)&w1s[SHIDX(jgt0+1, kt, l)];
                a0 = __builtin_amdgcn_mfma_f32_16x16x32_bf16(av, b0,  a0, 0, 0, 0);
                a1 = __builtin_amdgcn_mfma_f32_16x16x32_bf16(av, b1v, a1, 0, 0, 0);
            }
            #pragma unroll
            for (int kt = 0; kt < 16; kt++) {
                bf16x8 av  = LDA(A2, lr, lk, kt);
                bf16x8 b0  = *(const bf16x8*)&w2s[SHIDX(jgt0,   kt, l)];
                bf16x8 b1v = *(const bf16x8*)&w2s[SHIDX(jgt0+1, kt, l)];
                a0 = __builtin_amdgcn_mfma_f32_16x16x32_bf16(av, b0,  a0, 0, 0, 0);
                a1 = __builtin_amdgcn_mfma_f32_16x16x32_bf16(av, b1v, a1, 0, 0, 0);
            }
            #pragma unroll
            for (int r = 0; r < 4; r++) {
                scratch[(wid*16 + lk*4 + r)*33 + lr]      = a0[r];
                scratch[(wid*16 + lk*4 + r)*33 + 16 + lr] = a1[r];
            }
        }
        __syncthreads();
        #pragma unroll
        for (int s = 0; s < 2; s++) {
            int cell = tid + s*256;
            int row = cell >> 5, col = cell & 31;
            float gi = scratch[(0*16+row)*33 + col];
            float gf = scratch[(1*16+row)*33 + col];
            float gg = scratch[(2*16+row)*33 + col];
            float go = scratch[(3*16+row)*33 + col];
            float cold = s ? c11 : c10;
            float cn = sigf(gf)*cold + sigf(gi)*tanhf(gg);
            if (s) c11 = cn; else c10 = cn;
            hstage[cell] = f2b(sigf(go)*tanhf(cn));
        }
        __syncthreads();
        if (tid < 64) {
            int row = tid >> 2, cc = (tid & 3)*8;
            *(uint4*)&h1out[(size_t)(m0+row)*HH + hc0 + cc] = *(const uint4*)&hstage[row*32 + cc];
        }
        bseq++; team_barrier(cnt, bseq*16u);

        // ======== phase 3: head (redundant per block; keeps pos/cur local) ========
        stageA(A1, h1out, m0, tid);
        __syncthreads();
        {
            f32x4 hacc[4];
            #pragma unroll
            for (int q = 0; q < 4; q++) {
                #pragma unroll
                for (int r = 0; r < 4; r++) hacc[q][r] = ob1r[q];
            }
            #pragma unroll
            for (int kt = 0; kt < 16; kt++) {
                bf16x8 av = LDA(A1, lr, lk, kt);
                #pragma unroll
                for (int q = 0; q < 4; q++) {
                    bf16x8 bv = *(const bf16x8*)&ow1s[SHIDX(wid*4 + q, kt, l)];
                    hacc[q] = __builtin_amdgcn_mfma_f32_16x16x32_bf16(av, bv, hacc[q], 0, 0, 0);
                }
            }
            #pragma unroll
            for (int q = 0; q < 4; q++)
                #pragma unroll
                for (int r = 0; r < 4; r++)
                    scratch[(lk*4 + r)*257 + wid*64 + q*16 + lr] = leaky(hacc[q][r]);
        }
        __syncthreads();
        if (tid < 48) {
            int row = tid & 15, rr = tid >> 4;
            const float* w2r = ow2 + rr*256;
            float sum = 0.f;
            for (int kk = 0; kk < 256; kk++) {
                int k = (kk + row*16) & 255;
                sum += scratch[row*257 + k] * w2r[k];
            }
            osumS[row][rr] = sum + ob2[rr];
        }
        __syncthreads();
        if (tid < 16) {
            int row = tid;
            float o0 = osumS[row][0], o1 = osumS[row][1], o2 = osumS[row][2];
            float sp = (o2 > 20.f ? o2 : log1pf(expf(o2))) + 0.001f;
            posS[row][0] += o0; posS[row][1] += o1;
            if (ct == 0) {
                float* op = outp + ((size_t)(m0+row)*TT + t)*3;
                op[0] = o0; op[1] = o1; op[2] = sp;
            }
            float rx = endS[row][0]-posS[row][0], ry = endS[row][1]-posS[row][1];
            feats[row][0]=o0; feats[row][1]=o1; feats[row][2]=sp;
            feats[row][3]=rx; feats[row][4]=ry;
            feats[row][5]=sqrtf(rx*rx+ry*ry+1e-8f);
            feats[row][6]=atan2f(ry,rx);
        }
        __syncthreads();
    }
}

extern "C" void kernel_launch(void* const* d_in, const int* in_sizes, int n_in,
                              void* d_out, int out_size, void* d_ws, size_t ws_size,
                              hipStream_t stream)
{
    const float* start  = (const float*)d_in[0];
    const float* end    = (const float*)d_in[1];
    const float* z      = (const float*)d_in[2];
    const float* ce_w1  = (const float*)d_in[3];
    const float* ce_b1  = (const float*)d_in[4];
    const float* ce_g1  = (const float*)d_in[5];
    const float* ce_be1 = (const float*)d_in[6];
    const float* ce_w2  = (const float*)d_in[7];
    const float* ce_b2  = (const float*)d_in[8];
    const float* ce_g2  = (const float*)d_in[9];
    const float* ce_be2 = (const float*)d_in[10];
    const float* Wih0   = (const float*)d_in[11];
    const float* Whh0   = (const float*)d_in[12];
    const float* bih0   = (const float*)d_in[13];
    const float* bhh0   = (const float*)d_in[14];
    const float* Wih1   = (const float*)d_in[15];
    const float* Whh1   = (const float*)d_in[16];
    const float* bih1   = (const float*)d_in[17];
    const float* bhh1   = (const float*)d_in[18];
    const float* ow1    = (const float*)d_in[19];
    const float* ob1    = (const float*)d_in[20];
    const float* ow2    = (const float*)d_in[21];
    const float* ob2    = (const float*)d_in[22];
    const float* init_in= (const float*)d_in[23];
    const int*   max_len= (const int*)d_in[24];

    float* out = (float*)d_out;
    float* ws  = (float*)d_ws;
    size_t off = 0;
    float* gs0  = ws + off; off += (size_t)BB*G4;        // 2MB
    float* WfG  = ws + off; off += (size_t)G4*8;         // 64KB
    unsigned* bar = (unsigned*)(ws + off); off += 256;   // 1KB (16 teams x 64B)
    ushort* us = (ushort*)(ws + off);
    size_t uo = 0;
    ushort* w0s  = us + uo; uo += (size_t)G4*HH;         // 2MB
    ushort* w1s  = us + uo; uo += (size_t)G4*HH;
    ushort* w2s  = us + uo; uo += (size_t)G4*HH;
    ushort* wi0s = us + uo; uo += (size_t)G4*HH;
    ushort* ow1s = us + uo; uo += (size_t)256*HH;        // 256KB
    ushort* condb= us + uo; uo += (size_t)BB*HH;
    ushort* h0A  = us + uo; uo += (size_t)BB*HH;
    ushort* h0B  = us + uo; uo += (size_t)BB*HH;
    ushort* h1A  = us + uo; uo += (size_t)BB*HH;
    ushort* h1B  = us + uo; uo += (size_t)BB*HH;

    hipMemsetAsync(bar, 0, 256*sizeof(unsigned), stream);
    {
        size_t total = (size_t)4*1048576 + 131072 + 2048;
        prep_all<<<dim3((unsigned)((total + 255)/256)), dim3(256), 0, stream>>>(
            Whh0, Wih1, Whh1, Wih0, ow1, w0s, w1s, w2s, wi0s, ow1s, WfG);
    }
    cond_encoder<<<dim3(BB), dim3(256), 0, stream>>>(
        start, end, z, ce_w1, ce_b1, ce_g1, ce_be1, ce_w2, ce_b2, ce_g2, ce_be2, condb);
    gs0_mfma<<<dim3(256), dim3(256), 0, stream>>>(condb, wi0s, bih0, bhh0, gs0);

    rollout<<<dim3(256), dim3(256), 0, stream>>>(
        w0s, w1s, w2s, ow1s, gs0, WfG, bih1, bhh1, ob1, ow2, ob2,
        start, end, init_in, max_len, h0A, h0B, h1A, h1B, out, bar);
}

// Round 9
// 14705.063 us; speedup vs baseline: 1.3127x; 1.3127x over previous
//
#include <hip/hip_runtime.h>
#include <math.h>

#define BB 256
#define TT 256
#define HH 512
#define G4 2048
#define IN0_ 519

typedef __bf16 bf16x8 __attribute__((ext_vector_type(8)));
typedef float  f32x4  __attribute__((ext_vector_type(4)));
typedef unsigned short ushort;
typedef unsigned long long u64;

__device__ __forceinline__ float sigf(float x) { return 1.0f / (1.0f + expf(-x)); }
__device__ __forceinline__ float leaky(float x) { return x > 0.f ? x : 0.2f * x; }

__device__ __forceinline__ ushort f2b(float x) {
    union { float f; unsigned int u; } v; v.f = x;
    unsigned int r = v.u + 0x7fffu + ((v.u >> 16) & 1u);   // RNE
    return (ushort)(r >> 16);
}

__device__ __forceinline__ float block_sum(float v, float* red, int tid) {
    red[tid] = v; __syncthreads();
    for (int s = 128; s > 0; s >>= 1) {
        if (tid < s) red[tid] += red[tid + s];
        __syncthreads();
    }
    float r = red[0];
    __syncthreads();
    return r;
}

// swizzled LDS A-tile helpers: 16 rows x 512 bf16 (1KB/row), 16B granules
// byte offset within row bo, swizzle: bo ^ (((row ^ (bo>>6)) & 7) << 4)
#define SWZB(row, bo) ((bo) ^ (((((row) ^ ((bo) >> 6)) & 7)) << 4))
#define LDA(Abuf, lr_, lk_, kt_) \
    (*(const bf16x8*)&Abuf[((lr_) * 1024 + SWZB((lr_), (kt_)*64 + (lk_)*16)) >> 1])

// normal staging (kernel-boundary-published data only: condb)
__device__ __forceinline__ void stageA(ushort* dst, const ushort* src, int m0, int tid) {
    int row = tid >> 4;
    int lanebo = (tid & 15) * 64;
    const ushort* sp = src + (size_t)(m0 + row) * HH;
    #pragma unroll
    for (int j = 0; j < 4; j++) {
        int b2 = lanebo + j * 16;
        uint4 v = *(const uint4*)(sp + (b2 >> 1));
        *(uint4*)&dst[((row * 1024) + SWZB(row, b2)) >> 1] = v;
    }
}

// coherent staging for intra-step h exchange: relaxed agent-scope atomic loads
// bypass L1/L2 (coherent point = fabric/L3) -> no fences needed anywhere,
// local L2 (weights!) is never invalidated.
__device__ __forceinline__ void stage_at(ushort* dst, const ushort* src, int m0, int tid) {
    int row = tid >> 4;
    int lane = tid & 15;
    const u64* sp = (const u64*)(src + (size_t)(m0 + row) * HH) + lane * 8;
    #pragma unroll
    for (int j = 0; j < 8; j++) {
        u64 v = __hip_atomic_load(sp + j, __ATOMIC_RELAXED, __HIP_MEMORY_SCOPE_AGENT);
        int b2 = lane * 64 + j * 8;
        *(u64*)&dst[((row * 1024) + SWZB(row, b2)) >> 1] = v;
    }
}

// fence-free team barrier: relaxed atomics only. __syncthreads() before the
// add drains each wave's vmcnt (so this block's atomic h-stores are at the
// coherent point); reader loads issue only after the trailing __syncthreads.
__device__ __forceinline__ void team_barrier(unsigned* cnt, unsigned target) {
    __syncthreads();
    if (threadIdx.x == 0) {
        __hip_atomic_fetch_add(cnt, 1u, __ATOMIC_RELAXED, __HIP_MEMORY_SCOPE_AGENT);
        while (__hip_atomic_load(cnt, __ATOMIC_RELAXED, __HIP_MEMORY_SCOPE_AGENT) < target)
            __builtin_amdgcn_s_sleep(2);
    }
    __syncthreads();
}

// shuffled weight layout: idx = ((jgt*16 + kt)*64 + lane)*8 + e
// holds W[jgt*16 + (lane&15)][kt*32 + (lane>>4)*8 + e]
#define SHIDX(jgt, kt, l_) ((((size_t)(jgt) * 16 + (kt)) * 64 + (l_)) * 8)

// ---------------- prep: convert + shuffle all weights ----------------
__global__ __launch_bounds__(256) void prep_all(
    const float* __restrict__ Whh0, const float* __restrict__ Wih1,
    const float* __restrict__ Whh1, const float* __restrict__ Wih0,
    const float* __restrict__ ow1,
    ushort* __restrict__ w0s, ushort* __restrict__ w1s,
    ushort* __restrict__ w2s, ushort* __restrict__ wi0s,
    ushort* __restrict__ ow1s, float* __restrict__ Wf)
{
    size_t idx = (size_t)blockIdx.x * 256 + threadIdx.x;
    const size_t M = 1u << 20;
    if (idx < 4 * M) {
        int m = (int)(idx >> 20);
        unsigned i = (unsigned)(idx & (M - 1));
        int e = i & 7, ll = (i >> 3) & 63, kt = (i >> 9) & 15, jgt = i >> 13;
        int jg = jgt * 16 + (ll & 15);
        int k  = kt * 32 + ((ll >> 4) << 3) + e;
        float v;
        if (m == 0)      v = Whh0[(size_t)jg * 512 + k];
        else if (m == 1) v = Wih1[(size_t)jg * 512 + k];
        else if (m == 2) v = Whh1[(size_t)jg * 512 + k];
        else             v = Wih0[(size_t)jg * IN0_ + 3 + k];
        ushort* dst = (m == 0) ? w0s : (m == 1) ? w1s : (m == 2) ? w2s : wi0s;
        dst[i] = f2b(v);
    } else if (idx < 4 * M + 131072) {
        unsigned i = (unsigned)(idx - 4 * M);
        int e = i & 7, ll = (i >> 3) & 63, kt = (i >> 9) & 15, jgt = i >> 13; // jgt<16
        int jg = jgt * 16 + (ll & 15);
        int k  = kt * 32 + ((ll >> 4) << 3) + e;
        ow1s[i] = f2b(ow1[(size_t)jg * 512 + k]);
    } else if (idx < 4 * M + 131072 + 2048) {
        int jrow = (int)(idx - (4 * M + 131072));
        const int fc[7] = {0, 1, 2, 515, 516, 517, 518};
        #pragma unroll
        for (int f = 0; f < 7; f++) Wf[jrow * 8 + f] = Wih0[(size_t)jrow * IN0_ + fc[f]];
        Wf[jrow * 8 + 7] = 0.f;
    }
}

// ---------------- condition encoder (writes bf16 cond) ----------------
__global__ __launch_bounds__(256) void cond_encoder(
    const float* __restrict__ start, const float* __restrict__ end,
    const float* __restrict__ z,
    const float* __restrict__ w1, const float* __restrict__ b1,
    const float* __restrict__ g1, const float* __restrict__ be1,
    const float* __restrict__ w2, const float* __restrict__ b2,
    const float* __restrict__ g2, const float* __restrict__ be2,
    ushort* __restrict__ condb)
{
    __shared__ float ci[70];
    __shared__ float xr[512];
    __shared__ float red[256];
    int b = blockIdx.x, tid = threadIdx.x;
    if (tid == 0) {
        float sx = start[2*b], sy = start[2*b+1];
        float ex = end[2*b],   ey = end[2*b+1];
        float dx = ex - sx, dy = ey - sy;
        ci[0]=sx; ci[1]=sy; ci[2]=ex; ci[3]=ey;
        ci[4]=sqrtf(dx*dx + dy*dy + 1e-8f);
        ci[5]=atan2f(dy, dx);
    }
    if (tid < 64) ci[6+tid] = z[b*64 + tid];
    __syncthreads();

    float pre0 = b1[tid], pre1 = b1[tid+256];
    {
        const float* r0 = w1 + (size_t)tid*70;
        const float* r1 = w1 + (size_t)(tid+256)*70;
        for (int k = 0; k < 70; k++) { float c = ci[k]; pre0 += c*r0[k]; pre1 += c*r1[k]; }
    }
    float m = block_sum(pre0+pre1, red, tid) * (1.f/512.f);
    float d0 = pre0-m, d1 = pre1-m;
    float v = block_sum(d0*d0 + d1*d1, red, tid) * (1.f/512.f);
    float rstd = rsqrtf(v + 1e-5f);
    xr[tid]     = leaky(d0*rstd*g1[tid]     + be1[tid]);
    xr[tid+256] = leaky(d1*rstd*g1[tid+256] + be1[tid+256]);
    __syncthreads();

    float q0 = b2[tid], q1 = b2[tid+256];
    {
        const float4* r0 = (const float4*)(w2 + (size_t)tid*512);
        const float4* r1 = (const float4*)(w2 + (size_t)(tid+256)*512);
        const float4* xv4 = (const float4*)xr;
        for (int q = 0; q < 128; q++) {
            float4 xv = xv4[q];
            float4 wa = r0[q], wb = r1[q];
            q0 += xv.x*wa.x + xv.y*wa.y + xv.z*wa.z + xv.w*wa.w;
            q1 += xv.x*wb.x + xv.y*wb.y + xv.z*wb.z + xv.w*wb.w;
        }
    }
    m = block_sum(q0+q1, red, tid) * (1.f/512.f);
    d0 = q0-m; d1 = q1-m;
    v = block_sum(d0*d0 + d1*d1, red, tid) * (1.f/512.f);
    rstd = rsqrtf(v + 1e-5f);
    condb[(size_t)b*512 + tid]     = f2b(leaky(d0*rstd*g2[tid]     + be2[tid]));
    condb[(size_t)b*512 + tid+256] = f2b(leaky(d1*rstd*g2[tid+256] + be2[tid+256]));
}

// ---------------- gs0 = cond @ Wih0[:,3:515]^T + bih0 + bhh0 (MFMA) ----------------
__global__ __launch_bounds__(256) void gs0_mfma(
    const ushort* __restrict__ condb, const ushort* __restrict__ wi0s,
    const float* __restrict__ bih0, const float* __restrict__ bhh0,
    float* __restrict__ gs0)
{
    __shared__ ushort A1[16*512];
    int tid = threadIdx.x;
    int bt = blockIdx.x >> 4, ct2 = blockIdx.x & 15;
    int m0 = bt*16, hc0 = ct2*32;
    int wid = tid >> 6, l = tid & 63, lr = l & 15, lk = l >> 4;
    stageA(A1, condb, m0, tid);
    __syncthreads();
    int jgb = wid*512 + hc0;
    float bv0 = bih0[jgb+lr]    + bhh0[jgb+lr];
    float bv1 = bih0[jgb+16+lr] + bhh0[jgb+16+lr];
    f32x4 a0, a1;
    #pragma unroll
    for (int r = 0; r < 4; r++) { a0[r] = bv0; a1[r] = bv1; }
    int jgt = jgb >> 4;
    #pragma unroll
    for (int kt = 0; kt < 16; kt++) {
        bf16x8 av = LDA(A1, lr, lk, kt);
        bf16x8 b0 = *(const bf16x8*)&wi0s[SHIDX(jgt,   kt, l)];
        bf16x8 b1 = *(const bf16x8*)&wi0s[SHIDX(jgt+1, kt, l)];
        a0 = __builtin_amdgcn_mfma_f32_16x16x32_bf16(av, b0, a0, 0, 0, 0);
        a1 = __builtin_amdgcn_mfma_f32_16x16x32_bf16(av, b1, a1, 0, 0, 0);
    }
    #pragma unroll
    for (int r = 0; r < 4; r++) {
        gs0[(size_t)(m0 + lk*4 + r)*G4 + jgb + lr]      = a0[r];
        gs0[(size_t)(m0 + lk*4 + r)*G4 + jgb + 16 + lr] = a1[r];
    }
}

// ---------------- persistent rollout: 256 blocks, independent teams of 16 ----------------
__global__ __launch_bounds__(256, 1) void rollout(
    const ushort* __restrict__ w0s, const ushort* __restrict__ w1s,
    const ushort* __restrict__ w2s, const ushort* __restrict__ ow1s,
    const float* __restrict__ gs0, const float* __restrict__ WfG,
    const float* __restrict__ bih1, const float* __restrict__ bhh1,
    const float* __restrict__ ob1, const float* __restrict__ ow2,
    const float* __restrict__ ob2,
    const float* __restrict__ start, const float* __restrict__ endp,
    const float* __restrict__ init_in, const int* __restrict__ max_len,
    ushort* __restrict__ h0A, ushort* __restrict__ h0B,
    ushort* __restrict__ h1A, ushort* __restrict__ h1B,
    float* __restrict__ outp, unsigned* __restrict__ bar)
{
    __shared__ ushort A1[16*512];
    __shared__ ushort A2[16*512];
    __shared__ float scratch[16*257];       // gates [4][16][33] (phases 1/2) | hid [16][257] (phase 3)
    __shared__ float WfS[4*32*9];
    __shared__ ushort hstage[512];
    __shared__ float feats[16][8];
    __shared__ float posS[16][2], endS[16][2], osumS[16][3];

    int tid = threadIdx.x;
    int blk = blockIdx.x;
    int xcd = blk & 7, wi = blk >> 3;
    int ct = xcd*2 + (wi & 1);   // column-slice id: same-ct blocks share weights & an XCD
    int bt = wi >> 1;            // batch-tile id: team = all 16 ct's of this bt
    int m0 = bt*16, hc0 = ct*32;
    int wid = tid >> 6, l = tid & 63, lr = l & 15, lk = l >> 4;
    unsigned* cnt = bar + bt*16;

    for (int i = tid; i < 4*32*8; i += 256) {
        int g = i >> 8, rem = i & 255, col = rem >> 3, f = rem & 7;
        WfS[(g*32+col)*9 + f] = WfG[(size_t)(g*512 + hc0 + col)*8 + f];
    }
    if (tid < 16) {
        int b = m0 + tid;
        posS[tid][0] = start[2*b]; posS[tid][1] = start[2*b+1];
        endS[tid][0] = endp[2*b];  endS[tid][1] = endp[2*b+1];
        if (ct == 0) outp[(size_t)BB*TT*3 + b] = (float)max_len[0];
    }
    __syncthreads();
    if (tid < 16) {
        float rx = endS[tid][0]-posS[tid][0], ry = endS[tid][1]-posS[tid][1];
        feats[tid][0]=init_in[0]; feats[tid][1]=init_in[1]; feats[tid][2]=init_in[2];
        feats[tid][3]=rx; feats[tid][4]=ry;
        feats[tid][5]=sqrtf(rx*rx+ry*ry+1e-8f);
        feats[tid][6]=atan2f(ry,rx);
    }

    // one-time register state
    f32x4 gsr[2]; float b1r[2]; float ob1r[4];
    #pragma unroll
    for (int nt = 0; nt < 2; nt++) {
        int jg = wid*512 + hc0 + nt*16 + lr;
        #pragma unroll
        for (int r = 0; r < 4; r++) gsr[nt][r] = gs0[(size_t)(m0 + lk*4 + r)*G4 + jg];
        b1r[nt] = bih1[jg] + bhh1[jg];
    }
    #pragma unroll
    for (int q = 0; q < 4; q++) ob1r[q] = ob1[wid*64 + q*16 + lr];

    // zero own h slices via coherent atomic stores (plain stores would sit
    // dirty in local L2, invisible to remote bypassing atomic loads)
    if (tid < 128) {
        int row = tid >> 3, cc = (tid & 7) * 4;
        __hip_atomic_store((u64*)&h0A[(size_t)(m0+row)*HH + hc0 + cc], 0ull,
                           __ATOMIC_RELAXED, __HIP_MEMORY_SCOPE_AGENT);
        __hip_atomic_store((u64*)&h1A[(size_t)(m0+row)*HH + hc0 + cc], 0ull,
                           __ATOMIC_RELAXED, __HIP_MEMORY_SCOPE_AGENT);
    }
    float c00 = 0.f, c01 = 0.f, c10 = 0.f, c11 = 0.f;

    unsigned bseq = 1;
    team_barrier(cnt, bseq*16u);

    int jgt0 = wid*32 + ct*2;   // lstm weight-tile base
    #pragma unroll 1
    for (int t = 0; t < TT; t++) {
        const ushort* h0in  = (t & 1) ? h0B : h0A;
        ushort*       h0out = (t & 1) ? h0A : h0B;
        const ushort* h1in  = (t & 1) ? h1B : h1A;
        ushort*       h1out = (t & 1) ? h1A : h1B;

        // ======== phase 1: lstm0 ========
        stage_at(A1, h0in, m0, tid);
        __syncthreads();
        {
            f32x4 a0 = gsr[0], a1 = gsr[1];
            #pragma unroll
            for (int kt = 0; kt < 16; kt++) {
                bf16x8 av  = LDA(A1, lr, lk, kt);
                bf16x8 b0  = *(const bf16x8*)&w0s[SHIDX(jgt0,   kt, l)];
                bf16x8 b1v = *(const bf16x8*)&w0s[SHIDX(jgt0+1, kt, l)];
                a0 = __builtin_amdgcn_mfma_f32_16x16x32_bf16(av, b0,  a0, 0, 0, 0);
                a1 = __builtin_amdgcn_mfma_f32_16x16x32_bf16(av, b1v, a1, 0, 0, 0);
            }
            #pragma unroll
            for (int r = 0; r < 4; r++) {
                scratch[(wid*16 + lk*4 + r)*33 + lr]      = a0[r];
                scratch[(wid*16 + lk*4 + r)*33 + 16 + lr] = a1[r];
            }
        }
        __syncthreads();
        #pragma unroll
        for (int s = 0; s < 2; s++) {
            int cell = tid + s*256;
            int row = cell >> 5, col = cell & 31;
            float gv[4];
            #pragma unroll
            for (int g = 0; g < 4; g++) {
                float v = scratch[(g*16 + row)*33 + col];
                const float* wf = &WfS[(g*32 + col)*9];
                #pragma unroll
                for (int f = 0; f < 7; f++) v += feats[row][f] * wf[f];
                gv[g] = v;
            }
            float cold = s ? c01 : c00;
            float cn = sigf(gv[1])*cold + sigf(gv[0])*tanhf(gv[2]);
            if (s) c01 = cn; else c00 = cn;
            hstage[cell] = f2b(sigf(gv[3])*tanhf(cn));
        }
        __syncthreads();
        if (tid < 128) {
            int row = tid >> 3, cc = (tid & 7) * 4;
            u64 v = *(const u64*)&hstage[row*32 + cc];
            __hip_atomic_store((u64*)&h0out[(size_t)(m0+row)*HH + hc0 + cc], v,
                               __ATOMIC_RELAXED, __HIP_MEMORY_SCOPE_AGENT);
        }
        bseq++; team_barrier(cnt, bseq*16u);

        // ======== phase 2: lstm1 ========
        stage_at(A1, h0out, m0, tid);
        stage_at(A2, h1in,  m0, tid);
        __syncthreads();
        {
            f32x4 a0, a1;
            #pragma unroll
            for (int r = 0; r < 4; r++) { a0[r] = b1r[0]; a1[r] = b1r[1]; }
            #pragma unroll
            for (int kt = 0; kt < 16; kt++) {
                bf16x8 av  = LDA(A1, lr, lk, kt);
                bf16x8 b0  = *(const bf16x8*)&w1s[SHIDX(jgt0,   kt, l)];
                bf16x8 b1v = *(const bf16x8*)&w1s[SHIDX(jgt0+1, kt, l)];
                a0 = __builtin_amdgcn_mfma_f32_16x16x32_bf16(av, b0,  a0, 0, 0, 0);
                a1 = __builtin_amdgcn_mfma_f32_16x16x32_bf16(av, b1v, a1, 0, 0, 0);
            }
            #pragma unroll
            for (int kt = 0; kt < 16; kt++) {
                bf16x8 av  = LDA(A2, lr, lk, kt);
                bf16x8 b0  = *(const bf16x8*)&w2s[SHIDX(jgt0,   kt, l)];
                bf16x8 b1v = *(const bf16x8*)&w2s[SHIDX(jgt0+1, kt, l)];
                a0 = __builtin_amdgcn_mfma_f32_16x16x32_bf16(av, b0,  a0, 0, 0, 0);
                a1 = __builtin_amdgcn_mfma_f32_16x16x32_bf16(av, b1v, a1, 0, 0, 0);
            }
            #pragma unroll
            for (int r = 0; r < 4; r++) {
                scratch[(wid*16 + lk*4 + r)*33 + lr]      = a0[r];
                scratch[(wid*16 + lk*4 + r)*33 + 16 + lr] = a1[r];
            }
        }
        __syncthreads();
        #pragma unroll
        for (int s = 0; s < 2; s++) {
            int cell = tid + s*256;
            int row = cell >> 5, col = cell & 31;
            float gi = scratch[(0*16+row)*33 + col];
            float gf = scratch[(1*16+row)*33 + col];
            float gg = scratch[(2*16+row)*33 + col];
            float go = scratch[(3*16+row)*33 + col];
            float cold = s ? c11 : c10;
            float cn = sigf(gf)*cold + sigf(gi)*tanhf(gg);
            if (s) c11 = cn; else c10 = cn;
            hstage[cell] = f2b(sigf(go)*tanhf(cn));
        }
        __syncthreads();
        if (tid < 128) {
            int row = tid >> 3, cc = (tid & 7) * 4;
            u64 v = *(const u64*)&hstage[row*32 + cc];
            __hip_atomic_store((u64*)&h1out[(size_t)(m0+row)*HH + hc0 + cc], v,
                               __ATOMIC_RELAXED, __HIP_MEMORY_SCOPE_AGENT);
        }
        bseq++; team_barrier(cnt, bseq*16u);

        // ======== phase 3: head (redundant per block; keeps pos/cur local) ========
        stage_at(A1, h1out, m0, tid);
        __syncthreads();
        {
            f32x4 hacc[4];
            #pragma unroll
            for (int q = 0; q < 4; q++) {
                #pragma unroll
                for (int r = 0; r < 4; r++) hacc[q][r] = ob1r[q];
            }
            #pragma unroll
            for (int kt = 0; kt < 16; kt++) {
                bf16x8 av = LDA(A1, lr, lk, kt);
                #pragma unroll
                for (int q = 0; q < 4; q++) {
                    bf16x8 bv = *(const bf16x8*)&ow1s[SHIDX(wid*4 + q, kt, l)];
                    hacc[q] = __builtin_amdgcn_mfma_f32_16x16x32_bf16(av, bv, hacc[q], 0, 0, 0);
                }
            }
            #pragma unroll
            for (int q = 0; q < 4; q++)
                #pragma unroll
                for (int r = 0; r < 4; r++)
                    scratch[(lk*4 + r)*257 + wid*64 + q*16 + lr] = leaky(hacc[q][r]);
        }
        __syncthreads();
        if (tid < 48) {
            int row = tid & 15, rr = tid >> 4;
            const float* w2r = ow2 + rr*256;
            float sum = 0.f;
            for (int kk = 0; kk < 256; kk++) {
                int k = (kk + row*16) & 255;
                sum += scratch[row*257 + k] * w2r[k];
            }
            osumS[row][rr] = sum + ob2[rr];
        }
        __syncthreads();
        if (tid < 16) {
            int row = tid;
            float o0 = osumS[row][0], o1 = osumS[row][1], o2 = osumS[row][2];
            float sp = (o2 > 20.f ? o2 : log1pf(expf(o2))) + 0.001f;
            posS[row][0] += o0; posS[row][1] += o1;
            if (ct == 0) {
                float* op = outp + ((size_t)(m0+row)*TT + t)*3;
                op[0] = o0; op[1] = o1; op[2] = sp;
            }
            float rx = endS[row][0]-posS[row][0], ry = endS[row][1]-posS[row][1];
            feats[row][0]=o0; feats[row][1]=o1; feats[row][2]=sp;
            feats[row][3]=rx; feats[row][4]=ry;
            feats[row][5]=sqrtf(rx*rx+ry*ry+1e-8f);
            feats[row][6]=atan2f(ry,rx);
        }
        __syncthreads();
    }
}

extern "C" void kernel_launch(void* const* d_in, const int* in_sizes, int n_in,
                              void* d_out, int out_size, void* d_ws, size_t ws_size,
                              hipStream_t stream)
{
    const float* start  = (const float*)d_in[0];
    const float* end    = (const float*)d_in[1];
    const float* z      = (const float*)d_in[2];
    const float* ce_w1  = (const float*)d_in[3];
    const float* ce_b1  = (const float*)d_in[4];
    const float* ce_g1  = (const float*)d_in[5];
    const float* ce_be1 = (const float*)d_in[6];
    const float* ce_w2  = (const float*)d_in[7];
    const float* ce_b2  = (const float*)d_in[8];
    const float* ce_g2  = (const float*)d_in[9];
    const float* ce_be2 = (const float*)d_in[10];
    const float* Wih0   = (const float*)d_in[11];
    const float* Whh0   = (const float*)d_in[12];
    const float* bih0   = (const float*)d_in[13];
    const float* bhh0   = (const float*)d_in[14];
    const float* Wih1   = (const float*)d_in[15];
    const float* Whh1   = (const float*)d_in[16];
    const float* bih1   = (const float*)d_in[17];
    const float* bhh1   = (const float*)d_in[18];
    const float* ow1    = (const float*)d_in[19];
    const float* ob1    = (const float*)d_in[20];
    const float* ow2    = (const float*)d_in[21];
    const float* ob2    = (const float*)d_in[22];
    const float* init_in= (const float*)d_in[23];
    const int*   max_len= (const int*)d_in[24];

    float* out = (float*)d_out;
    float* ws  = (float*)d_ws;
    size_t off = 0;
    float* gs0  = ws + off; off += (size_t)BB*G4;        // 2MB
    float* WfG  = ws + off; off += (size_t)G4*8;         // 64KB
    unsigned* bar = (unsigned*)(ws + off); off += 256;   // 1KB (16 teams x 64B)
    ushort* us = (ushort*)(ws + off);
    size_t uo = 0;
    ushort* w0s  = us + uo; uo += (size_t)G4*HH;         // 2MB
    ushort* w1s  = us + uo; uo += (size_t)G4*HH;
    ushort* w2s  = us + uo; uo += (size_t)G4*HH;
    ushort* wi0s = us + uo; uo += (size_t)G4*HH;
    ushort* ow1s = us + uo; uo += (size_t)256*HH;        // 256KB
    ushort* condb= us + uo; uo += (size_t)BB*HH;
    ushort* h0A  = us + uo; uo += (size_t)BB*HH;
    ushort* h0B  = us + uo; uo += (size_t)BB*HH;
    ushort* h1A  = us + uo; uo += (size_t)BB*HH;
    ushort* h1B  = us + uo; uo += (size_t)BB*HH;

    hipMemsetAsync(bar, 0, 256*sizeof(unsigned), stream);
    {
        size_t total = (size_t)4*1048576 + 131072 + 2048;
        prep_all<<<dim3((unsigned)((total + 255)/256)), dim3(256), 0, stream>>>(
            Whh0, Wih1, Whh1, Wih0, ow1, w0s, w1s, w2s, wi0s, ow1s, WfG);
    }
    cond_encoder<<<dim3(BB), dim3(256), 0, stream>>>(
        start, end, z, ce_w1, ce_b1, ce_g1, ce_be1, ce_w2, ce_b2, ce_g2, ce_be2, condb);
    gs0_mfma<<<dim3(256), dim3(256), 0, stream>>>(condb, wi0s, bih0, bhh0, gs0);

    rollout<<<dim3(256), dim3(256), 0, stream>>>(
        w0s, w1s, w2s, ow1s, gs0, WfG, bih1, bhh1, ob1, ow2, ob2,
        start, end, init_in, max_len, h0A, h0B, h1A, h1B, out, bar);
}